// Round 9
// baseline (983.104 us; speedup 1.0000x reference)
//
#include <hip/hip_runtime.h>
#include <hip/hip_bf16.h>
#include <stdint.h>

// Problem constants (NicheST): N=4096, IN_DIM=3000, H1=512, D=64, K_sub=32, E=49152, HEADS=4
#define NN      4096
#define INDIM   3000
#define H1DIM   512
#define DDIM    64
#define RECON_ELEMS (NN * INDIM)

typedef __attribute__((ext_vector_type(8))) __bf16          bf16x8;
typedef __attribute__((ext_vector_type(8))) unsigned short  u16x8;
typedef __attribute__((ext_vector_type(4))) float           f32x4;
typedef __attribute__((ext_vector_type(4))) unsigned int    u32x4;

__device__ __forceinline__ unsigned short f2bf(float f) {
  union { float f; unsigned int i; } v; v.f = f;
  unsigned int x = v.i;
  unsigned int lsb = (x >> 16) & 1u;
  x += 0x7FFFu + lsb;                  // round-to-nearest-even
  return (unsigned short)(x >> 16);
}

// ---------------------------------------------------------------------------
// Threefry-2x32 (JAX-compatible, 20 rounds)
// ---------------------------------------------------------------------------
__device__ __forceinline__ void tf2x32(unsigned k0, unsigned k1, unsigned x0, unsigned x1,
                                       unsigned &o0, unsigned &o1) {
  unsigned ks2 = k0 ^ k1 ^ 0x1BD11BDAu;
  x0 += k0; x1 += k1;
#define TFR(r) { x0 += x1; x1 = (x1 << (r)) | (x1 >> (32 - (r))); x1 ^= x0; }
  TFR(13) TFR(15) TFR(26) TFR(6)
  x0 += k1; x1 += ks2 + 1u;
  TFR(17) TFR(29) TFR(16) TFR(24)
  x0 += ks2; x1 += k0 + 2u;
  TFR(13) TFR(15) TFR(26) TFR(6)
  x0 += k0; x1 += k1 + 3u;
  TFR(17) TFR(29) TFR(16) TFR(24)
  x0 += k1; x1 += ks2 + 4u;
  TFR(13) TFR(15) TFR(26) TFR(6)
  x0 += ks2; x1 += k0 + 5u;
#undef TFR
  o0 = x0; o1 = x1;
}

// ---------------------------------------------------------------------------
// Graph preprocessing
// ---------------------------------------------------------------------------
__global__ void k_deg(const int* __restrict__ dst, int* __restrict__ cnt, int E) {
  int e = blockIdx.x * 256 + threadIdx.x;
  if (e < E) atomicAdd(&cnt[dst[e]], 1);
}

__global__ void k_inv(const int* __restrict__ cnt, float* __restrict__ inv) {
  int n = blockIdx.x * 256 + threadIdx.x;
  if (n < NN) inv[n] = 1.0f / sqrtf((float)cnt[n] + 1.0f);
}

__global__ __launch_bounds__(1024) void k_scan(const int* __restrict__ cnt, int* __restrict__ offs) {
  __shared__ int ssum[1024];
  int tid = threadIdx.x;
  int c0 = cnt[tid*4], c1 = cnt[tid*4+1], c2 = cnt[tid*4+2], c3 = cnt[tid*4+3];
  int s = c0 + c1 + c2 + c3;
  ssum[tid] = s;
  __syncthreads();
  for (int off = 1; off < 1024; off <<= 1) {
    int v = (tid >= off) ? ssum[tid - off] : 0;
    __syncthreads();
    ssum[tid] += v;
    __syncthreads();
  }
  int base = ssum[tid] - s;  // exclusive prefix
  offs[tid*4]   = base;
  offs[tid*4+1] = base + c0;
  offs[tid*4+2] = base + c0 + c1;
  offs[tid*4+3] = base + c0 + c1 + c2;
  if (tid == 1023) offs[4096] = ssum[1023];
}

__global__ void k_scatter(const int* __restrict__ dst, const int* __restrict__ offs,
                          int* __restrict__ cur, int* __restrict__ eid, int E) {
  int e = blockIdx.x * 256 + threadIdx.x;
  if (e < E) {
    int d = dst[e];
    int pos = offs[d] + atomicAdd(&cur[d], 1);
    eid[pos] = e;
  }
}

// sort each node's edge list ascending by edge id -> deterministic accumulation
__global__ void k_sort(const int* __restrict__ offs, int* __restrict__ eid) {
  int n = blockIdx.x * 256 + threadIdx.x;
  if (n >= NN) return;
  int b = offs[n], e = offs[n+1];
  for (int i = b + 1; i < e; i++) {
    int v = eid[i]; int j = i - 1;
    while (j >= b && eid[j] > v) { eid[j+1] = eid[j]; j--; }
    eid[j+1] = v;
  }
}

// ---------------------------------------------------------------------------
// fp32 GEMM (conv1): C_z = x[4096,3000] @ w1[3000,512] over K-slice z.
// 128x128 tile, BK=16, 256 thr, 8x8/thread (2x2 blocks of 4x4). Split-K=2.
// v11: double-buffered LDS + register prefetch, 1 barrier/tile (was 2).
// Per-thread FMA order unchanged -> bit-identical output.
// ---------------------------------------------------------------------------
#define FBK 16
__global__ __launch_bounds__(256) void k_gemm_f32(
    const float* __restrict__ A, const float* __restrict__ B, float* __restrict__ C) {
  __shared__ float As[2][FBK * 132];
  __shared__ float Bs[2][FBK * 132];
  const int tid = threadIdx.x;
  const int m0 = blockIdx.y * 128;
  const int n0 = blockIdx.x * 128;
  const int z  = blockIdx.z;
  const int kBeg = z ? 1504 : 0;
  const int kEnd = z ? 3000 : 1504;
  C += (size_t)z * NN * 512;
  const int lane = tid & 63, w = tid >> 6;
  const int rg = w * 4 + (lane >> 4);  // 0..15 row group
  const int cg = lane & 15;            // 0..15 col group
  f32x4 acc[2][2][4];
#pragma unroll
  for (int a = 0; a < 2; a++)
#pragma unroll
    for (int b = 0; b < 2; b++)
#pragma unroll
      for (int i = 0; i < 4; i++) acc[a][b][i] = (f32x4){0.f,0.f,0.f,0.f};

  const int arow = tid & 127;
  const int asl  = tid >> 7;   // 0..1
  const int bkr  = tid >> 4;   // 0..15
  const int bcq  = tid & 15;   // 0..15

  f32x4 ra[2], rb0, rb1;
  // prologue: load tile kBeg into registers
  {
    const int kt = kBeg;
    const bool full = (kt + FBK <= kEnd);
#pragma unroll
    for (int it = 0; it < 2; it++) {
      int kk = (asl * 2 + it) * 4;
      if (full) {
        ra[it] = *(const f32x4*)(A + (size_t)(m0 + arow) * INDIM + kt + kk);
      } else {
#pragma unroll
        for (int j = 0; j < 4; j++)
          ra[it][j] = (kt + kk + j < kEnd) ? A[(size_t)(m0 + arow) * INDIM + kt + kk + j] : 0.f;
      }
    }
    if (full || kt + bkr < kEnd) {
      const float* bp = B + (size_t)(kt + bkr) * 512 + n0 + bcq * 8;
      rb0 = *(const f32x4*)bp;
      rb1 = *(const f32x4*)(bp + 4);
    } else { rb0 = (f32x4){0.f,0.f,0.f,0.f}; rb1 = rb0; }
  }

  int buf = 0;
  for (int kt = kBeg; kt < kEnd; kt += FBK) {
    // stage registers -> LDS[buf]
#pragma unroll
    for (int it = 0; it < 2; it++) {
      int kk = (asl * 2 + it) * 4;
      As[buf][(kk+0)*132 + arow] = ra[it][0];
      As[buf][(kk+1)*132 + arow] = ra[it][1];
      As[buf][(kk+2)*132 + arow] = ra[it][2];
      As[buf][(kk+3)*132 + arow] = ra[it][3];
    }
    *(f32x4*)&Bs[buf][bkr*132 + bcq*8]     = rb0;
    *(f32x4*)&Bs[buf][bkr*132 + bcq*8 + 4] = rb1;
    __syncthreads();
    // prefetch next tile into registers (lands while computing this tile)
    const int ktn = kt + FBK;
    if (ktn < kEnd) {
      const bool fulln = (ktn + FBK <= kEnd);
#pragma unroll
      for (int it = 0; it < 2; it++) {
        int kk = (asl * 2 + it) * 4;
        if (fulln) {
          ra[it] = *(const f32x4*)(A + (size_t)(m0 + arow) * INDIM + ktn + kk);
        } else {
#pragma unroll
          for (int j = 0; j < 4; j++)
            ra[it][j] = (ktn + kk + j < kEnd) ? A[(size_t)(m0 + arow) * INDIM + ktn + kk + j] : 0.f;
        }
      }
      if (fulln || ktn + bkr < kEnd) {
        const float* bp = B + (size_t)(ktn + bkr) * 512 + n0 + bcq * 8;
        rb0 = *(const f32x4*)bp;
        rb1 = *(const f32x4*)(bp + 4);
      } else { rb0 = (f32x4){0.f,0.f,0.f,0.f}; rb1 = rb0; }
    }
    const float* Asb = As[buf];
    const float* Bsb = Bs[buf];
#pragma unroll
    for (int k = 0; k < FBK; k++) {
      f32x4 a0 = *(const f32x4*)&Asb[k*132 + rg*4];
      f32x4 a1 = *(const f32x4*)&Asb[k*132 + 64 + rg*4];
      f32x4 b0 = *(const f32x4*)&Bsb[k*132 + cg*4];
      f32x4 b1 = *(const f32x4*)&Bsb[k*132 + 64 + cg*4];
#pragma unroll
      for (int i = 0; i < 4; i++)
#pragma unroll
        for (int j = 0; j < 4; j++) {
          acc[0][0][i][j] = fmaf(a0[i], b0[j], acc[0][0][i][j]);
          acc[0][1][i][j] = fmaf(a0[i], b1[j], acc[0][1][i][j]);
          acc[1][0][i][j] = fmaf(a1[i], b0[j], acc[1][0][i][j]);
          acc[1][1][i][j] = fmaf(a1[i], b1[j], acc[1][1][i][j]);
        }
    }
    // no second barrier: next iteration writes buf^1; a wave can only pass the
    // next barrier after ALL waves finished this tile's compute.
    buf ^= 1;
  }
#pragma unroll
  for (int a = 0; a < 2; a++)
#pragma unroll
    for (int i = 0; i < 4; i++) {
      int gr = m0 + a*64 + rg*4 + i;
#pragma unroll
      for (int b = 0; b < 2; b++)
        *(f32x4*)(C + (size_t)gr * 512 + n0 + b*64 + cg*4) = acc[a][b][i];
    }
}

// deterministic split-K combine: c0 += c1 (in place)
__global__ void k_combine(float* __restrict__ c0, const float* __restrict__ c1) {
  int i = blockIdx.x * 256 + threadIdx.x;
  ((f32x4*)c0)[i] = ((const f32x4*)c0)[i] + ((const f32x4*)c1)[i];
}

// ---------------------------------------------------------------------------
// bf16 MFMA GEMM (decoder): A bf16 [M,K], B f32 [K,N] converted on the fly.
// mode 1: +bias, ReLU, bf16 out. mode 2: +bias, f32 out.  K must be mult of 32.
// ---------------------------------------------------------------------------
__global__ __launch_bounds__(256) void k_gemm_bf(
    const unsigned short* __restrict__ A, const float* __restrict__ B,
    float* __restrict__ Cf, unsigned short* __restrict__ Cb,
    const float* __restrict__ bias,
    int M, int N, int K, int ldc, int mode) {
  __shared__ __attribute__((aligned(16))) unsigned short As[128 * 40];
  __shared__ __attribute__((aligned(16))) unsigned short Bs[128 * 40];
  const int tid  = threadIdx.x;
  const int m0   = blockIdx.y * 128;
  const int n0   = blockIdx.x * 128;
  const int lane = tid & 63;
  const int wid  = tid >> 6;
  const int wm   = wid >> 1, wn = wid & 1;
  const int lrow = lane & 15, lk = lane >> 4;

  f32x4 acc[4][4];
#pragma unroll
  for (int i = 0; i < 4; i++)
#pragma unroll
    for (int j = 0; j < 4; j++) acc[i][j] = (f32x4){0.f, 0.f, 0.f, 0.f};

  for (int k0 = 0; k0 < K; k0 += 32) {
    // stage A (already bf16)
#pragma unroll
    for (int it = 0; it < 2; it++) {
      int c   = it * 256 + tid;
      int row = c >> 2, kc = c & 3;
      int kg  = k0 + kc * 8;
      u16x8 v = *(const u16x8*)(A + (size_t)(m0 + row) * K + kg);
      *(u16x8*)&As[row * 40 + kc * 8] = v;
    }
    // stage B transposed, f32 -> bf16
    {
      int kk_ = tid & 31;
      int nc0 = tid >> 5;
      int kg  = k0 + kk_;
#pragma unroll
      for (int it = 0; it < 2; it++) {
        int nc = nc0 + it * 8;
        int ng = n0 + nc * 8;
        unsigned short vb[8];
        if (ng + 8 <= N) {
          f32x4 f0 = *(const f32x4*)(B + (size_t)kg * N + ng);
          f32x4 f1 = *(const f32x4*)(B + (size_t)kg * N + ng + 4);
#pragma unroll
          for (int j = 0; j < 4; j++) { vb[j] = f2bf(f0[j]); vb[4+j] = f2bf(f1[j]); }
        } else {
#pragma unroll
          for (int j = 0; j < 8; j++)
            vb[j] = (ng + j < N) ? f2bf(B[(size_t)kg * N + ng + j]) : (unsigned short)0;
        }
#pragma unroll
        for (int j = 0; j < 8; j++) Bs[(nc * 8 + j) * 40 + kk_] = vb[j];
      }
    }
    __syncthreads();
    bf16x8 af[4], bfr[4];
#pragma unroll
    for (int mi = 0; mi < 4; mi++) {
      u16x8 r = *(const u16x8*)&As[(wm * 64 + mi * 16 + lrow) * 40 + lk * 8];
      af[mi] = __builtin_bit_cast(bf16x8, r);
    }
#pragma unroll
    for (int ni = 0; ni < 4; ni++) {
      u16x8 r = *(const u16x8*)&Bs[(wn * 64 + ni * 16 + lrow) * 40 + lk * 8];
      bfr[ni] = __builtin_bit_cast(bf16x8, r);
    }
#pragma unroll
    for (int mi = 0; mi < 4; mi++)
#pragma unroll
      for (int ni = 0; ni < 4; ni++)
        acc[mi][ni] = __builtin_amdgcn_mfma_f32_16x16x32_bf16(af[mi], bfr[ni], acc[mi][ni], 0, 0, 0);
    __syncthreads();
  }

#pragma unroll
  for (int mi = 0; mi < 4; mi++)
#pragma unroll
    for (int ni = 0; ni < 4; ni++)
#pragma unroll
      for (int reg = 0; reg < 4; reg++) {
        int gr = m0 + wm * 64 + mi * 16 + lk * 4 + reg;
        int gc = n0 + wn * 64 + ni * 16 + lrow;
        if (gc < N) {
          float v = acc[mi][ni][reg] + bias[gc];
          if (mode == 1) {
            if (v < 0.f) v = 0.f;
            Cb[(size_t)gr * ldc + gc] = f2bf(v);
          } else {
            Cf[(size_t)gr * ldc + gc] = v;
          }
        }
      }
}

// ---------------------------------------------------------------------------
// GCN aggregation (deterministic edge order), f32
// ---------------------------------------------------------------------------
__global__ __launch_bounds__(256) void k_agg(
    const float* __restrict__ X, float* __restrict__ Y,
    const float* __restrict__ bias, const int* __restrict__ offs,
    const int* __restrict__ eid, const int* __restrict__ esrc,
    const float* __restrict__ inv, int F, int relu) {
  int n = blockIdx.x;
  int beg = offs[n], end = offs[n + 1];
  float invn = inv[n];
  float inv2 = invn * invn;
  for (int d = threadIdx.x; d < F; d += 256) {
    float acc = 0.f;
    for (int t = beg; t < end; t++) {
      int e = eid[t]; int s = esrc[e];
      float cf = inv[s] * invn;
      acc += X[(size_t)s * F + d] * cf;
    }
    acc += X[(size_t)n * F + d] * inv2;
    acc += bias[d];
    if (relu && acc < 0.f) acc = 0.f;
    Y[(size_t)n * F + d] = acc;
  }
}

// hw2[4096,64] = h[4096,512] @ enc_w2[512,64], all f32 (ranking path)
__global__ __launch_bounds__(256) void k_mmw2(const float* __restrict__ h,
                                              const float* __restrict__ w2,
                                              float* __restrict__ out) {
  __shared__ float hs[4 * 512];
  int tid  = threadIdx.x;
  int brow = blockIdx.x * 4;
  const f32x4* src = (const f32x4*)(h + (size_t)brow * 512);
  f32x4* dst4 = (f32x4*)hs;
  dst4[tid]       = src[tid];
  dst4[tid + 256] = src[tid + 256];
  __syncthreads();
  int r = tid >> 6, c = tid & 63;
  float acc = 0.f;
  const float* hr = hs + r * 512;
#pragma unroll 8
  for (int k = 0; k < 512; k++) acc = fmaf(hr[k], w2[k * 64 + c], acc);
  out[(size_t)(brow + r) * 64 + c] = acc;
}

// local[n] = mean over 32 sub_nodes of spot_emb (+ bf16 copy for decoder)
__global__ void k_pool(const float* __restrict__ spot, const int* __restrict__ sub,
                       float* __restrict__ local, unsigned short* __restrict__ local_bf) {
  int n = blockIdx.x, d = threadIdx.x;  // 64 threads
  float acc = 0.f;
  for (int j = 0; j < 32; j++) {
    int s = sub[n * 32 + j];
    acc += spot[(size_t)s * 64 + d];
  }
  float lv = acc * 0.03125f;
  local[(size_t)n * 64 + d] = lv;
  local_bf[(size_t)n * 64 + d] = f2bf(lv);
}

// Q/K/V packed rows: Qp/Kp/Vp[n][64] = local[n] @ in_w^T + in_b (f32)
__global__ void k_qkv(const float* __restrict__ local, const float* __restrict__ iw,
                      const float* __restrict__ ib,
                      float* __restrict__ Qp, float* __restrict__ Kp, float* __restrict__ Vp) {
  __shared__ float lx[64];
  int n = blockIdx.x, t = threadIdx.x;  // 192 threads
  if (t < 64) lx[t] = local[(size_t)n * 64 + t];
  __syncthreads();
  float acc = 0.f;
#pragma unroll 8
  for (int d = 0; d < 64; d++) acc = fmaf(lx[d], iw[t * 64 + d], acc);
  acc += ib[t];
  if (t < 64)       Qp[(size_t)n * 64 + t] = acc;
  else if (t < 128) Kp[(size_t)n * 64 + (t - 64)] = acc;
  else              Vp[(size_t)n * 64 + (t - 128)] = acc;
}

// ---------------------------------------------------------------------------
// Fused attention v12: BOTH passes in shuffle form -- main loops barrier-free.
// Thread (stm=t>>4, stc=t&15; hsel=stc>>2, rr=stc&3) owns, per tile:
// head hsel, key slot stm+16*rr, both q. Pass 1 = v11 (proven). Pass 2:
// same butterfly scores -> p = __expf(s*0.25 - M)*iZ; rowavg = gather 4 head
// p's via lane-addressed shfl, summed in the OLD left-assoc head order,
// bounced through rvS[2][16][64] to select-owner threads (2 barriers per
// 16-tile super-block); PV accumulated per-thread into o[2][16] registers
// (V[key][hsel*16..+16] reads = 16 full 256B rows/wave, coalesced), reduced
// in the epilogue over the 64 key-slots in fixed ascending order (ctx is the
// tolerance path). KtB/Pt staging and 120 of 128 barriers deleted.
// Numerics: p from tree-summed dots (~1e-7/key, same class as pass-1/__expf
// changes that passed). If FAIL: revert pass 2 to v11 staged form.
// ---------------------------------------------------------------------------
#define RT 2
__global__ __launch_bounds__(256, 3) void k_attn(
    const float* __restrict__ Qp, const float* __restrict__ Kp, const float* __restrict__ Vp,
    float* __restrict__ ctx, int* __restrict__ sampled) {
  // smem (17.4 KB): pass1 redM/redZ [1024]; epilogue Osh [256][17]; select histT/gaux
  __shared__ __attribute__((aligned(16))) float smem[256 * 17];
  __shared__ __attribute__((aligned(16))) float rvS[2 * 16 * 64];  // 8 KB rowavg bounce
  __shared__ float sMZ[2][2][4];   // [M/Z][q][h]
  __shared__ unsigned wtot[4];
  __shared__ unsigned sh_prefix;
  __shared__ int sh_r;

  const int t   = threadIdx.x;
  const int n0  = blockIdx.x * RT;
  const int stm = t >> 4;      // 0..15
  const int stc = t & 15;      // 0..15
  const int wv  = t >> 6;      // wave id
  const int lane = t & 63;
  const int hsel = stc >> 2;   // head handled by this thread
  const int rr   = stc & 3;    // lane's key slot = stm + 16*rr

  // Q fragment: dims stc*4..+4 for both q (pass 1 AND pass 2 use this)
  float qsh[2][4];
#pragma unroll
  for (int q = 0; q < 2; q++) {
    f32x4 qv = *(const f32x4*)(Qp + (size_t)(n0 + q) * 64 + stc * 4);
    qsh[q][0] = qv[0]; qsh[q][1] = qv[1]; qsh[q][2] = qv[2]; qsh[q][3] = qv[3];
  }

  // ---- pass 1 (shuffle form): online M, Z -- no LDS, no barriers ----
  float M[2] = {-3.0e38f, -3.0e38f}, Z[2] = {0.f, 0.f};
  {
    f32x4 ka[4], kb[4];
#pragma unroll
    for (int j = 0; j < 4; j++) {
      ka[j] = *(const f32x4*)(Kp + (size_t)(j * 16 + stm) * 64 + stc * 4);
      kb[j] = *(const f32x4*)(Kp + (size_t)(64 + j * 16 + stm) * 64 + stc * 4);
    }
    for (int tp = 0; tp < 64; tp += 2) {
#pragma unroll
      for (int half = 0; half < 2; half++) {
        f32x4 k0 = (half == 0) ? ka[0] : kb[0];
        f32x4 k1 = (half == 0) ? ka[1] : kb[1];
        f32x4 k2 = (half == 0) ? ka[2] : kb[2];
        f32x4 k3 = (half == 0) ? ka[3] : kb[3];
        float s00 = 0.f, s01 = 0.f, s02 = 0.f, s03 = 0.f;
        float s10 = 0.f, s11 = 0.f, s12 = 0.f, s13 = 0.f;
#pragma unroll
        for (int e = 0; e < 4; e++) {
          s00 = fmaf(qsh[0][e], k0[e], s00);
          s01 = fmaf(qsh[0][e], k1[e], s01);
          s02 = fmaf(qsh[0][e], k2[e], s02);
          s03 = fmaf(qsh[0][e], k3[e], s03);
          s10 = fmaf(qsh[1][e], k0[e], s10);
          s11 = fmaf(qsh[1][e], k1[e], s11);
          s12 = fmaf(qsh[1][e], k2[e], s12);
          s13 = fmaf(qsh[1][e], k3[e], s13);
        }
        if (tp + 2 + half < 64) {
#pragma unroll
          for (int j = 0; j < 4; j++) {
            f32x4 v = *(const f32x4*)(Kp + (size_t)((tp + 2 + half) * 64 + j * 16 + stm) * 64 + stc * 4);
            if (half == 0) ka[j] = v; else kb[j] = v;
          }
        }
        s00 += __shfl_xor(s00, 1, 64); s00 += __shfl_xor(s00, 2, 64);
        s01 += __shfl_xor(s01, 1, 64); s01 += __shfl_xor(s01, 2, 64);
        s02 += __shfl_xor(s02, 1, 64); s02 += __shfl_xor(s02, 2, 64);
        s03 += __shfl_xor(s03, 1, 64); s03 += __shfl_xor(s03, 2, 64);
        s10 += __shfl_xor(s10, 1, 64); s10 += __shfl_xor(s10, 2, 64);
        s11 += __shfl_xor(s11, 1, 64); s11 += __shfl_xor(s11, 2, 64);
        s12 += __shfl_xor(s12, 1, 64); s12 += __shfl_xor(s12, 2, 64);
        s13 += __shfl_xor(s13, 1, 64); s13 += __shfl_xor(s13, 2, 64);
        float sv0 = (rr == 0) ? s00 : (rr == 1) ? s01 : (rr == 2) ? s02 : s03;
        float sv1 = (rr == 0) ? s10 : (rr == 1) ? s11 : (rr == 2) ? s12 : s13;
        sv0 *= 0.25f; sv1 *= 0.25f;
        if (sv0 > M[0]) { Z[0] = fmaf(Z[0], __expf(M[0] - sv0), 1.0f); M[0] = sv0; }
        else            Z[0] += __expf(sv0 - M[0]);
        if (sv1 > M[1]) { Z[1] = fmaf(Z[1], __expf(M[1] - sv1), 1.0f); M[1] = sv1; }
        else            Z[1] += __expf(sv1 - M[1]);
      }
    }
  }
  // merge M/Z: rows (q*4+h), slot stm+16*rr -- identical partition to v10/v11.
  {
    float* redM = smem;
    float* redZ = smem + 512;
    int slot = stm + 16 * rr;
    redM[(0 * 4 + hsel) * 64 + slot] = M[0];
    redM[(1 * 4 + hsel) * 64 + slot] = M[1];
    redZ[(0 * 4 + hsel) * 64 + slot] = Z[0];
    redZ[(1 * 4 + hsel) * 64 + slot] = Z[1];
    __syncthreads();
    if (t < 8) {
      const float* pm = &redM[t * 64];
      const float* pz = &redZ[t * 64];
      float Mv = -3.0e38f, Zv = 0.f;
      for (int i = 0; i < 64; i++) {
        float m_ = pm[i], z_ = pz[i];
        if (m_ > Mv) { Zv = fmaf(Zv, __expf(Mv - m_), z_); Mv = m_; }
        else         Zv = fmaf(z_, __expf(m_ - Mv), Zv);
      }
      sMZ[0][t >> 2][t & 3] = Mv;
      sMZ[1][t >> 2][t & 3] = Zv;
    }
    __syncthreads();
  }
  // this thread needs only its own head's stats
  float Mh2[2], iZ2[2];
#pragma unroll
  for (int q = 0; q < 2; q++) {
    Mh2[q] = sMZ[0][q][hsel];
    iZ2[q] = 1.0f / sMZ[1][q][hsel];
  }

  // ---- pass 2 (shuffle form): p, rowavg->rvS, PV into registers ----
  float o[2][16];
#pragma unroll
  for (int q = 0; q < 2; q++)
#pragma unroll
    for (int d = 0; d < 16; d++) o[q][d] = 0.f;
  float rv[2][16];

  {
    f32x4 ka[4], kb[4];
#pragma unroll
    for (int j = 0; j < 4; j++) {
      ka[j] = *(const f32x4*)(Kp + (size_t)(j * 16 + stm) * 64 + stc * 4);
      kb[j] = *(const f32x4*)(Kp + (size_t)(64 + j * 16 + stm) * 64 + stc * 4);
    }
    for (int sb = 0; sb < 4; sb++) {
      for (int tp = 0; tp < 16; tp += 2) {
#pragma unroll
        for (int half = 0; half < 2; half++) {
          const int ti   = tp + half;
          const int tile = sb * 16 + ti;
          f32x4 k0 = (half == 0) ? ka[0] : kb[0];
          f32x4 k1 = (half == 0) ? ka[1] : kb[1];
          f32x4 k2 = (half == 0) ? ka[2] : kb[2];
          f32x4 k3 = (half == 0) ? ka[3] : kb[3];
          float s00 = 0.f, s01 = 0.f, s02 = 0.f, s03 = 0.f;
          float s10 = 0.f, s11 = 0.f, s12 = 0.f, s13 = 0.f;
#pragma unroll
          for (int e = 0; e < 4; e++) {
            s00 = fmaf(qsh[0][e], k0[e], s00);
            s01 = fmaf(qsh[0][e], k1[e], s01);
            s02 = fmaf(qsh[0][e], k2[e], s02);
            s03 = fmaf(qsh[0][e], k3[e], s03);
            s10 = fmaf(qsh[1][e], k0[e], s10);
            s11 = fmaf(qsh[1][e], k1[e], s11);
            s12 = fmaf(qsh[1][e], k2[e], s12);
            s13 = fmaf(qsh[1][e], k3[e], s13);
          }
          if (tile + 2 < 64) {
#pragma unroll
            for (int j = 0; j < 4; j++) {
              f32x4 v = *(const f32x4*)(Kp + (size_t)((tile + 2) * 64 + j * 16 + stm) * 64 + stc * 4);
              if (half == 0) ka[j] = v; else kb[j] = v;
            }
          }
          s00 += __shfl_xor(s00, 1, 64); s00 += __shfl_xor(s00, 2, 64);
          s01 += __shfl_xor(s01, 1, 64); s01 += __shfl_xor(s01, 2, 64);
          s02 += __shfl_xor(s02, 1, 64); s02 += __shfl_xor(s02, 2, 64);
          s03 += __shfl_xor(s03, 1, 64); s03 += __shfl_xor(s03, 2, 64);
          s10 += __shfl_xor(s10, 1, 64); s10 += __shfl_xor(s10, 2, 64);
          s11 += __shfl_xor(s11, 1, 64); s11 += __shfl_xor(s11, 2, 64);
          s12 += __shfl_xor(s12, 1, 64); s12 += __shfl_xor(s12, 2, 64);
          s13 += __shfl_xor(s13, 1, 64); s13 += __shfl_xor(s13, 2, 64);
          float sv0 = (rr == 0) ? s00 : (rr == 1) ? s01 : (rr == 2) ? s02 : s03;
          float sv1 = (rr == 0) ? s10 : (rr == 1) ? s11 : (rr == 2) ? s12 : s13;
          float p0 = __expf(sv0 * 0.25f - Mh2[0]) * iZ2[0];
          float p1 = __expf(sv1 * 0.25f - Mh2[1]) * iZ2[1];
          // rowavg: gather heads 1..3 to hsel==0 lanes; sum in OLD head order
          int lbase = lane & 48;
          int lrr   = lane & 3;
          float g01 = __shfl(p0, lbase | (4 + lrr), 64);
          float g02 = __shfl(p0, lbase | (8 + lrr), 64);
          float g03 = __shfl(p0, lbase | (12 + lrr), 64);
          float g11 = __shfl(p1, lbase | (4 + lrr), 64);
          float g12 = __shfl(p1, lbase | (8 + lrr), 64);
          float g13 = __shfl(p1, lbase | (12 + lrr), 64);
          if (hsel == 0) {
            int slot = stm + 16 * rr;
            rvS[(0 * 16 + ti) * 64 + slot] = 0.25f * (((p0 + g01) + g02) + g03);
            rvS[(1 * 16 + ti) * 64 + slot] = 0.25f * (((p1 + g11) + g12) + g13);
          }
          // PV: p x V[key][hsel*16..+16]
          {
            const float* vp = Vp + (size_t)(tile * 64 + stm + 16 * rr) * 64 + hsel * 16;
            f32x4 v0 = *(const f32x4*)(vp);
            f32x4 v1 = *(const f32x4*)(vp + 4);
            f32x4 v2 = *(const f32x4*)(vp + 8);
            f32x4 v3 = *(const f32x4*)(vp + 12);
#pragma unroll
            for (int e = 0; e < 4; e++) {
              o[0][e]      = fmaf(p0, v0[e], o[0][e]);
              o[0][4 + e]  = fmaf(p0, v1[e], o[0][4 + e]);
              o[0][8 + e]  = fmaf(p0, v2[e], o[0][8 + e]);
              o[0][12 + e] = fmaf(p0, v3[e], o[0][12 + e]);
              o[1][e]      = fmaf(p1, v0[e], o[1][e]);
              o[1][4 + e]  = fmaf(p1, v1[e], o[1][4 + e]);
              o[1][8 + e]  = fmaf(p1, v2[e], o[1][8 + e]);
              o[1][12 + e] = fmaf(p1, v3[e], o[1][12 + e]);
            }
          }
        }
      }
      // super-block done: owner wave captures its rowavg slice
      __syncthreads();
      if (wv == sb) {
#pragma unroll
        for (int g = 0; g < 16; g++) {
          rv[0][g] = rvS[(0 * 16 + g) * 64 + lane];
          rv[1][g] = rvS[(1 * 16 + g) * 64 + lane];
        }
      }
      __syncthreads();   // rvS free for next super-block
    }
  }

  // ---- PV reduction over the 64 key-slots (fixed ascending order) ----
#pragma unroll
  for (int q = 0; q < 2; q++) {
#pragma unroll
    for (int d = 0; d < 16; d++) smem[t * 17 + d] = o[q][d];
    __syncthreads();
    if (t < 64) {
      int hh = t >> 4, d = t & 15;
      float acc = 0.f;
      for (int s = 0; s < 64; s++) {
        int to = (s & 15) * 16 + hh * 4 + (s >> 4);   // owner thread of slot s, head hh
        acc += smem[to * 17 + d];
      }
      ctx[(size_t)(n0 + q) * 64 + t] = acc;
    }
    __syncthreads();
  }

  // ---- per-row radix select from REGISTERS (Threefry rank; ties -> lowest) ----
  unsigned* histT = (unsigned*)smem;             // [4][256]
  unsigned* gaux  = ((unsigned*)smem) + 1024;    // gcnts[64] @0, gpref[64] @64
#pragma unroll
  for (int q = 0; q < RT; q++) {
    int n = n0 + q;
    if (t == 0) {
      unsigned a0, a1, b0, b1;
      tf2x32(0u, 42u, 0u, 2u, a0, a1);
      tf2x32(0u, 42u, 1u, 3u, b0, b1);
      unsigned o0, o1, bits;
      if (n < 2048) { tf2x32(a1, b1, (unsigned)n, (unsigned)(n + 2048), o0, o1); bits = o0; }
      else          { tf2x32(a1, b1, (unsigned)(n - 2048), (unsigned)n, o0, o1); bits = o1; }
      sh_r = (int)(bits & 1023u);
      sh_prefix = 0u;
    }
    __syncthreads();
    int r = sh_r;
    unsigned prefix = 0u;
    for (int level = 0; level < 4; level++) {
      int shift = 24 - 8 * level;
      unsigned c0 = 0, c1 = 0, c2 = 0, c3 = 0;
#pragma unroll
      for (int g = 0; g < 16; g++) {
        unsigned u = __float_as_uint(rv[q][g]);
        bool ok = (level == 0) || ((u >> (shift + 8)) == (prefix >> (shift + 8)));
        unsigned bin = (u >> shift) & 255u;
        unsigned long long mok = __ballot(ok);
        unsigned long long b0 = __ballot(bin & 1u);
        unsigned long long b1 = __ballot(bin & 2u);
        unsigned long long b2 = __ballot(bin & 4u);
        unsigned long long b3 = __ballot(bin & 8u);
        unsigned long long b4 = __ballot(bin & 16u);
        unsigned long long b5 = __ballot(bin & 32u);
        unsigned long long b6 = __ballot(bin & 64u);
        unsigned long long b7 = __ballot(bin & 128u);
        unsigned long long m = mok;
        m &= (lane & 1)  ? b0 : ~b0;
        m &= (lane & 2)  ? b1 : ~b1;
        m &= (lane & 4)  ? b2 : ~b2;
        m &= (lane & 8)  ? b3 : ~b3;
        m &= (lane & 16) ? b4 : ~b4;
        m &= (lane & 32) ? b5 : ~b5;
        c0 += (unsigned)__builtin_popcountll(m & ~b6 & ~b7);
        c1 += (unsigned)__builtin_popcountll(m &  b6 & ~b7);
        c2 += (unsigned)__builtin_popcountll(m & ~b6 &  b7);
        c3 += (unsigned)__builtin_popcountll(m &  b6 &  b7);
      }
      histT[wv * 256 + lane]       = c0;
      histT[wv * 256 + 64 + lane]  = c1;
      histT[wv * 256 + 128 + lane] = c2;
      histT[wv * 256 + 192 + lane] = c3;
      __syncthreads();
      unsigned own = histT[t] + histT[256 + t] + histT[512 + t] + histT[768 + t];
      unsigned v = own;
      for (int off = 1; off < 64; off <<= 1) {
        unsigned u2 = __shfl_up(v, off, 64);
        if ((t & 63) >= off) v += u2;
      }
      if ((t & 63) == 63) wtot[t >> 6] = v;
      __syncthreads();
      unsigned basev = 0;
#pragma unroll
      for (int w = 0; w < 4; w++) if (w < (t >> 6)) basev += wtot[w];
      v += basev;
      unsigned cb = v - own;
      if ((unsigned)r >= cb && (unsigned)r < v) {
        sh_prefix = prefix | ((unsigned)t << shift);
        sh_r = r - (int)cb;
      }
      __syncthreads();
      prefix = sh_prefix; r = sh_r;
    }
    // extraction: rank-r among {idx : bits(idx)==prefix}, ascending idx
    {
      unsigned long long msk[16];
#pragma unroll
      for (int g = 0; g < 16; g++)
        msk[g] = __ballot(__float_as_uint(rv[q][g]) == prefix);
      if (lane == 0) {
#pragma unroll
        for (int g = 0; g < 16; g++)
          gaux[wv * 16 + g] = (unsigned)__builtin_popcountll(msk[g]);
      }
      __syncthreads();
      if (t < 64) {
        unsigned acc = 0;
        for (int i = 0; i < t; i++) acc += gaux[i];
        gaux[64 + t] = acc;
      }
      __syncthreads();
#pragma unroll
      for (int g = 0; g < 16; g++) {
        if (__float_as_uint(rv[q][g]) == prefix) {
          unsigned before = (unsigned)__builtin_popcountll(msk[g] & ((1ull << lane) - 1ull));
          if ((int)(gaux[64 + wv * 16 + g] + before) == r)
            sampled[n] = (wv * 16 + g) * 64 + lane;
        }
      }
      __syncthreads();
    }
  }
}

// global_niches = ctx @ out_w^T + out_b  (f32)
__global__ void k_outproj(const float* __restrict__ ctx, const float* __restrict__ ow,
                          const float* __restrict__ ob, float* __restrict__ gni) {
  __shared__ float cx[64];
  int n = blockIdx.x, t = threadIdx.x;  // 64 threads
  cx[t] = ctx[(size_t)n * 64 + t];
  __syncthreads();
  float acc = 0.f;
#pragma unroll 8
  for (int j = 0; j < 64; j++) acc = fmaf(cx[j], ow[t * 64 + j], acc);
  gni[(size_t)n * 64 + t] = acc + ob[t];
}

// bilinear discriminator logits (pos & neg), f32 outputs
__global__ void k_logits(const float* __restrict__ local, const float* __restrict__ gni,
                         const int* __restrict__ sampled,
                         const float* __restrict__ bw, const float* __restrict__ bb,
                         float* __restrict__ outp, float* __restrict__ outn) {
  __shared__ float lv[64], gp[64], gn[64];
  int n = blockIdx.x, t = threadIdx.x;  // 64 threads
  int sm = sampled[n];
  lv[t] = local[(size_t)n * 64 + t];
  gp[t] = gni[(size_t)n * 64 + t];
  gn[t] = gni[(size_t)sm * 64 + t];
  __syncthreads();
  float tp = 0.f, tn = 0.f;
#pragma unroll 8
  for (int e = 0; e < 64; e++) {
    float w = bw[t * 64 + e];
    tp = fmaf(w, gp[e], tp);
    tn = fmaf(w, gn[e], tn);
  }
  float vp = lv[t] * tp, vn = lv[t] * tn;
  for (int off = 32; off; off >>= 1) {
    vp += __shfl_down(vp, off, 64);
    vn += __shfl_down(vn, off, 64);
  }
  if (t == 0) {
    outp[n] = vp + bb[0];
    outn[n] = vn + bb[0];
  }
}

// ---------------------------------------------------------------------------
extern "C" void kernel_launch(void* const* d_in, const int* in_sizes, int n_in,
                              void* d_out, int out_size, void* d_ws, size_t ws_size,
                              hipStream_t stream) {
  const float* x      = (const float*)d_in[0];
  const int*   edge   = (const int*)d_in[1];
  const int*   sub    = (const int*)d_in[2];
  const float* enc_w1 = (const float*)d_in[3];
  const float* enc_b1 = (const float*)d_in[4];
  const float* enc_w2 = (const float*)d_in[5];
  const float* enc_b2 = (const float*)d_in[6];
  const float* dec_w1 = (const float*)d_in[7];
  const float* dec_b1 = (const float*)d_in[8];
  const float* dec_w2 = (const float*)d_in[9];
  const float* dec_b2 = (const float*)d_in[10];
  const float* ain_w  = (const float*)d_in[11];
  const float* ain_b  = (const float*)d_in[12];
  const float* aout_w = (const float*)d_in[13];
  const float* aout_b = (const float*)d_in[14];
  const float* bil_w  = (const float*)d_in[15];
  const float* bil_b  = (const float*)d_in[16];
  float* out = (float*)d_out;

  const int E = in_sizes[1] / 2;  // 49152
  const int* esrc = edge;
  const int* edst = edge + E;

  // ---- time-overlapped workspace (~19.8 MB) ----
  char* base = (char*)d_ws;
  const size_t MB = (size_t)1 << 20;
  float*          cpart    = (float*)(base + 0);             // [conv1..combine] 16MB (2 x 8MB)
  float*          h_pre    = (float*)(base + 0);             // = cpart slice 0, [combine..agg1]
  unsigned short* dech_bf  = (unsigned short*)(base + 0);    // [dec1..dec2] 4MB
  float*          h        = (float*)(base + 8*MB);          // [agg1..mmw2] 8MB
  float*          Qp       = (float*)(base + 8*MB);          // [qkv..attn] 1MB
  float*          Kp       = (float*)(base + 9*MB);          // [qkv..attn] 1MB
  float*          Vp       = (float*)(base + 10*MB);         // [qkv..attn] 1MB
  float*          ctx      = (float*)(base + 11*MB);         // [attn..outproj] 1MB
  float*          gni      = (float*)(base + 12*MB);         // [outproj..logits] 1MB
  float*          hw2      = (float*)(base + 16*MB);         // [mmw2..agg2] 1MB
  float*          spot     = (float*)(base + 17*MB);         // [agg2..pool] 1MB
  float*          localf   = (float*)(base + 18*MB);         // [pool..logits] 1MB
  unsigned short* local_bf = (unsigned short*)(base + 19*MB);// [pool..dec1] 0.5MB
  char* ip = base + 19*MB + 512*1024;
  float* inv    = (float*)ip;  ip += 16384;
  int*   degcnt = (int*)ip;    ip += 16384;  // zeroed
  int*   cursor = (int*)ip;    ip += 16384;  // zeroed
  int*   offs   = (int*)ip;    ip += 16640;
  int*   sampled= (int*)ip;    ip += 16384;
  int*   eid    = (int*)ip;    ip += (size_t)E * 4;

  hipMemsetAsync(degcnt, 0, (size_t)NN * 4, stream);
  hipMemsetAsync(cursor, 0, (size_t)NN * 4, stream);

  int egrid = (E + 255) / 256;
  k_deg<<<egrid, 256, 0, stream>>>(edst, degcnt, E);
  k_inv<<<(NN + 255) / 256, 256, 0, stream>>>(degcnt, inv);
  k_scan<<<1, 1024, 0, stream>>>(degcnt, offs);
  k_scatter<<<egrid, 256, 0, stream>>>(edst, offs, cursor, eid, E);
  k_sort<<<(NN + 255) / 256, 256, 0, stream>>>(offs, eid);

  // encoder conv1: f32, split-K=2 + deterministic combine
  {
    dim3 g(4, 32, 2);
    k_gemm_f32<<<g, 256, 0, stream>>>(x, enc_w1, cpart);
  }
  k_combine<<<(NN * 512 / 4) / 256, 256, 0, stream>>>(h_pre, cpart + (size_t)NN * 512);
  k_agg<<<NN, 256, 0, stream>>>(h_pre, h, enc_b1, offs, eid, esrc, inv, 512, 1);
  k_mmw2<<<NN / 4, 256, 0, stream>>>(h, enc_w2, hw2);
  k_agg<<<NN, 256, 0, stream>>>(hw2, spot, enc_b2, offs, eid, esrc, inv, 64, 0);
  k_pool<<<NN, 64, 0, stream>>>(spot, sub, localf, local_bf);

  // decoder (bf16 MFMA, f32 weights converted on the fly)
  {
    dim3 g(4, 32);
    k_gemm_bf<<<g, 256, 0, stream>>>(local_bf, dec_w1, nullptr, dech_bf, dec_b1,
                                     NN, 512, 64, 512, 1);
  }
  {
    dim3 g(24, 32);
    k_gemm_bf<<<g, 256, 0, stream>>>(dech_bf, dec_w2, out, nullptr, dec_b2,
                                     NN, INDIM, 512, INDIM, 2);
  }

  // attention (f32 ranking path, fused stats+avg+ctx+select)
  k_qkv<<<NN, 192, 0, stream>>>(localf, ain_w, ain_b, Qp, Kp, Vp);
  k_attn<<<NN / RT, 256, 0, stream>>>(Qp, Kp, Vp, ctx, sampled);
  k_outproj<<<NN, 64, 0, stream>>>(ctx, aout_w, aout_b, gni);
  k_logits<<<NN, 64, 0, stream>>>(localf, gni, sampled, bil_w, bil_b,
                                  out + RECON_ELEMS, out + RECON_ELEMS + NN);
}

// Round 10
// 916.735 us; speedup vs baseline: 1.0724x; 1.0724x over previous
//
#include <hip/hip_runtime.h>
#include <hip/hip_bf16.h>
#include <stdint.h>

// Problem constants (NicheST): N=4096, IN_DIM=3000, H1=512, D=64, K_sub=32, E=49152, HEADS=4
#define NN      4096
#define INDIM   3000
#define H1DIM   512
#define DDIM    64
#define RECON_ELEMS (NN * INDIM)

typedef __attribute__((ext_vector_type(8))) __bf16          bf16x8;
typedef __attribute__((ext_vector_type(8))) unsigned short  u16x8;
typedef __attribute__((ext_vector_type(4))) float           f32x4;
typedef __attribute__((ext_vector_type(4))) unsigned int    u32x4;

__device__ __forceinline__ unsigned short f2bf(float f) {
  union { float f; unsigned int i; } v; v.f = f;
  unsigned int x = v.i;
  unsigned int lsb = (x >> 16) & 1u;
  x += 0x7FFFu + lsb;                  // round-to-nearest-even
  return (unsigned short)(x >> 16);
}

// ---------------------------------------------------------------------------
// Threefry-2x32 (JAX-compatible, 20 rounds)
// ---------------------------------------------------------------------------
__device__ __forceinline__ void tf2x32(unsigned k0, unsigned k1, unsigned x0, unsigned x1,
                                       unsigned &o0, unsigned &o1) {
  unsigned ks2 = k0 ^ k1 ^ 0x1BD11BDAu;
  x0 += k0; x1 += k1;
#define TFR(r) { x0 += x1; x1 = (x1 << (r)) | (x1 >> (32 - (r))); x1 ^= x0; }
  TFR(13) TFR(15) TFR(26) TFR(6)
  x0 += k1; x1 += ks2 + 1u;
  TFR(17) TFR(29) TFR(16) TFR(24)
  x0 += ks2; x1 += k0 + 2u;
  TFR(13) TFR(15) TFR(26) TFR(6)
  x0 += k0; x1 += k1 + 3u;
  TFR(17) TFR(29) TFR(16) TFR(24)
  x0 += k1; x1 += ks2 + 4u;
  TFR(13) TFR(15) TFR(26) TFR(6)
  x0 += ks2; x1 += k0 + 5u;
#undef TFR
  o0 = x0; o1 = x1;
}

// ---------------------------------------------------------------------------
// Graph preprocessing
// ---------------------------------------------------------------------------
__global__ void k_deg(const int* __restrict__ dst, int* __restrict__ cnt, int E) {
  int e = blockIdx.x * 256 + threadIdx.x;
  if (e < E) atomicAdd(&cnt[dst[e]], 1);
}

__global__ void k_inv(const int* __restrict__ cnt, float* __restrict__ inv) {
  int n = blockIdx.x * 256 + threadIdx.x;
  if (n < NN) inv[n] = 1.0f / sqrtf((float)cnt[n] + 1.0f);
}

__global__ __launch_bounds__(1024) void k_scan(const int* __restrict__ cnt, int* __restrict__ offs) {
  __shared__ int ssum[1024];
  int tid = threadIdx.x;
  int c0 = cnt[tid*4], c1 = cnt[tid*4+1], c2 = cnt[tid*4+2], c3 = cnt[tid*4+3];
  int s = c0 + c1 + c2 + c3;
  ssum[tid] = s;
  __syncthreads();
  for (int off = 1; off < 1024; off <<= 1) {
    int v = (tid >= off) ? ssum[tid - off] : 0;
    __syncthreads();
    ssum[tid] += v;
    __syncthreads();
  }
  int base = ssum[tid] - s;  // exclusive prefix
  offs[tid*4]   = base;
  offs[tid*4+1] = base + c0;
  offs[tid*4+2] = base + c0 + c1;
  offs[tid*4+3] = base + c0 + c1 + c2;
  if (tid == 1023) offs[4096] = ssum[1023];
}

__global__ void k_scatter(const int* __restrict__ dst, const int* __restrict__ offs,
                          int* __restrict__ cur, int* __restrict__ eid, int E) {
  int e = blockIdx.x * 256 + threadIdx.x;
  if (e < E) {
    int d = dst[e];
    int pos = offs[d] + atomicAdd(&cur[d], 1);
    eid[pos] = e;
  }
}

// sort each node's edge list ascending by edge id -> deterministic accumulation
__global__ void k_sort(const int* __restrict__ offs, int* __restrict__ eid) {
  int n = blockIdx.x * 256 + threadIdx.x;
  if (n >= NN) return;
  int b = offs[n], e = offs[n+1];
  for (int i = b + 1; i < e; i++) {
    int v = eid[i]; int j = i - 1;
    while (j >= b && eid[j] > v) { eid[j+1] = eid[j]; j--; }
    eid[j+1] = v;
  }
}

// ---------------------------------------------------------------------------
// fp32 GEMM (conv1): C_z = x[4096,3000] @ w1[3000,512] over K-slice z.
// 128x128 tile, BK=16, 256 thr, 8x8/thread (2x2 blocks of 4x4). Split-K=2.
// v11: double-buffered LDS + register prefetch, 1 barrier/tile (was 2).
// Per-thread FMA order unchanged -> bit-identical output.
// ---------------------------------------------------------------------------
#define FBK 16
__global__ __launch_bounds__(256) void k_gemm_f32(
    const float* __restrict__ A, const float* __restrict__ B, float* __restrict__ C) {
  __shared__ float As[2][FBK * 132];
  __shared__ float Bs[2][FBK * 132];
  const int tid = threadIdx.x;
  const int m0 = blockIdx.y * 128;
  const int n0 = blockIdx.x * 128;
  const int z  = blockIdx.z;
  const int kBeg = z ? 1504 : 0;
  const int kEnd = z ? 3000 : 1504;
  C += (size_t)z * NN * 512;
  const int lane = tid & 63, w = tid >> 6;
  const int rg = w * 4 + (lane >> 4);  // 0..15 row group
  const int cg = lane & 15;            // 0..15 col group
  f32x4 acc[2][2][4];
#pragma unroll
  for (int a = 0; a < 2; a++)
#pragma unroll
    for (int b = 0; b < 2; b++)
#pragma unroll
      for (int i = 0; i < 4; i++) acc[a][b][i] = (f32x4){0.f,0.f,0.f,0.f};

  const int arow = tid & 127;
  const int asl  = tid >> 7;   // 0..1
  const int bkr  = tid >> 4;   // 0..15
  const int bcq  = tid & 15;   // 0..15

  f32x4 ra[2], rb0, rb1;
  // prologue: load tile kBeg into registers
  {
    const int kt = kBeg;
    const bool full = (kt + FBK <= kEnd);
#pragma unroll
    for (int it = 0; it < 2; it++) {
      int kk = (asl * 2 + it) * 4;
      if (full) {
        ra[it] = *(const f32x4*)(A + (size_t)(m0 + arow) * INDIM + kt + kk);
      } else {
#pragma unroll
        for (int j = 0; j < 4; j++)
          ra[it][j] = (kt + kk + j < kEnd) ? A[(size_t)(m0 + arow) * INDIM + kt + kk + j] : 0.f;
      }
    }
    if (full || kt + bkr < kEnd) {
      const float* bp = B + (size_t)(kt + bkr) * 512 + n0 + bcq * 8;
      rb0 = *(const f32x4*)bp;
      rb1 = *(const f32x4*)(bp + 4);
    } else { rb0 = (f32x4){0.f,0.f,0.f,0.f}; rb1 = rb0; }
  }

  int buf = 0;
  for (int kt = kBeg; kt < kEnd; kt += FBK) {
    // stage registers -> LDS[buf]
#pragma unroll
    for (int it = 0; it < 2; it++) {
      int kk = (asl * 2 + it) * 4;
      As[buf][(kk+0)*132 + arow] = ra[it][0];
      As[buf][(kk+1)*132 + arow] = ra[it][1];
      As[buf][(kk+2)*132 + arow] = ra[it][2];
      As[buf][(kk+3)*132 + arow] = ra[it][3];
    }
    *(f32x4*)&Bs[buf][bkr*132 + bcq*8]     = rb0;
    *(f32x4*)&Bs[buf][bkr*132 + bcq*8 + 4] = rb1;
    __syncthreads();
    // prefetch next tile into registers (lands while computing this tile)
    const int ktn = kt + FBK;
    if (ktn < kEnd) {
      const bool fulln = (ktn + FBK <= kEnd);
#pragma unroll
      for (int it = 0; it < 2; it++) {
        int kk = (asl * 2 + it) * 4;
        if (fulln) {
          ra[it] = *(const f32x4*)(A + (size_t)(m0 + arow) * INDIM + ktn + kk);
        } else {
#pragma unroll
          for (int j = 0; j < 4; j++)
            ra[it][j] = (ktn + kk + j < kEnd) ? A[(size_t)(m0 + arow) * INDIM + ktn + kk + j] : 0.f;
        }
      }
      if (fulln || ktn + bkr < kEnd) {
        const float* bp = B + (size_t)(ktn + bkr) * 512 + n0 + bcq * 8;
        rb0 = *(const f32x4*)bp;
        rb1 = *(const f32x4*)(bp + 4);
      } else { rb0 = (f32x4){0.f,0.f,0.f,0.f}; rb1 = rb0; }
    }
    const float* Asb = As[buf];
    const float* Bsb = Bs[buf];
#pragma unroll
    for (int k = 0; k < FBK; k++) {
      f32x4 a0 = *(const f32x4*)&Asb[k*132 + rg*4];
      f32x4 a1 = *(const f32x4*)&Asb[k*132 + 64 + rg*4];
      f32x4 b0 = *(const f32x4*)&Bsb[k*132 + cg*4];
      f32x4 b1 = *(const f32x4*)&Bsb[k*132 + 64 + cg*4];
#pragma unroll
      for (int i = 0; i < 4; i++)
#pragma unroll
        for (int j = 0; j < 4; j++) {
          acc[0][0][i][j] = fmaf(a0[i], b0[j], acc[0][0][i][j]);
          acc[0][1][i][j] = fmaf(a0[i], b1[j], acc[0][1][i][j]);
          acc[1][0][i][j] = fmaf(a1[i], b0[j], acc[1][0][i][j]);
          acc[1][1][i][j] = fmaf(a1[i], b1[j], acc[1][1][i][j]);
        }
    }
    // no second barrier: next iteration writes buf^1; a wave can only pass the
    // next barrier after ALL waves finished this tile's compute.
    buf ^= 1;
  }
#pragma unroll
  for (int a = 0; a < 2; a++)
#pragma unroll
    for (int i = 0; i < 4; i++) {
      int gr = m0 + a*64 + rg*4 + i;
#pragma unroll
      for (int b = 0; b < 2; b++)
        *(f32x4*)(C + (size_t)gr * 512 + n0 + b*64 + cg*4) = acc[a][b][i];
    }
}

// deterministic split-K combine: c0 += c1 (in place)
__global__ void k_combine(float* __restrict__ c0, const float* __restrict__ c1) {
  int i = blockIdx.x * 256 + threadIdx.x;
  ((f32x4*)c0)[i] = ((const f32x4*)c0)[i] + ((const f32x4*)c1)[i];
}

// ---------------------------------------------------------------------------
// bf16 MFMA GEMM (decoder): A bf16 [M,K], B f32 [K,N] converted on the fly.
// mode 1: +bias, ReLU, bf16 out. mode 2: +bias, f32 out.  K must be mult of 32.
// ---------------------------------------------------------------------------
__global__ __launch_bounds__(256) void k_gemm_bf(
    const unsigned short* __restrict__ A, const float* __restrict__ B,
    float* __restrict__ Cf, unsigned short* __restrict__ Cb,
    const float* __restrict__ bias,
    int M, int N, int K, int ldc, int mode) {
  __shared__ __attribute__((aligned(16))) unsigned short As[128 * 40];
  __shared__ __attribute__((aligned(16))) unsigned short Bs[128 * 40];
  const int tid  = threadIdx.x;
  const int m0   = blockIdx.y * 128;
  const int n0   = blockIdx.x * 128;
  const int lane = tid & 63;
  const int wid  = tid >> 6;
  const int wm   = wid >> 1, wn = wid & 1;
  const int lrow = lane & 15, lk = lane >> 4;

  f32x4 acc[4][4];
#pragma unroll
  for (int i = 0; i < 4; i++)
#pragma unroll
    for (int j = 0; j < 4; j++) acc[i][j] = (f32x4){0.f, 0.f, 0.f, 0.f};

  for (int k0 = 0; k0 < K; k0 += 32) {
    // stage A (already bf16)
#pragma unroll
    for (int it = 0; it < 2; it++) {
      int c   = it * 256 + tid;
      int row = c >> 2, kc = c & 3;
      int kg  = k0 + kc * 8;
      u16x8 v = *(const u16x8*)(A + (size_t)(m0 + row) * K + kg);
      *(u16x8*)&As[row * 40 + kc * 8] = v;
    }
    // stage B transposed, f32 -> bf16
    {
      int kk_ = tid & 31;
      int nc0 = tid >> 5;
      int kg  = k0 + kk_;
#pragma unroll
      for (int it = 0; it < 2; it++) {
        int nc = nc0 + it * 8;
        int ng = n0 + nc * 8;
        unsigned short vb[8];
        if (ng + 8 <= N) {
          f32x4 f0 = *(const f32x4*)(B + (size_t)kg * N + ng);
          f32x4 f1 = *(const f32x4*)(B + (size_t)kg * N + ng + 4);
#pragma unroll
          for (int j = 0; j < 4; j++) { vb[j] = f2bf(f0[j]); vb[4+j] = f2bf(f1[j]); }
        } else {
#pragma unroll
          for (int j = 0; j < 8; j++)
            vb[j] = (ng + j < N) ? f2bf(B[(size_t)kg * N + ng + j]) : (unsigned short)0;
        }
#pragma unroll
        for (int j = 0; j < 8; j++) Bs[(nc * 8 + j) * 40 + kk_] = vb[j];
      }
    }
    __syncthreads();
    bf16x8 af[4], bfr[4];
#pragma unroll
    for (int mi = 0; mi < 4; mi++) {
      u16x8 r = *(const u16x8*)&As[(wm * 64 + mi * 16 + lrow) * 40 + lk * 8];
      af[mi] = __builtin_bit_cast(bf16x8, r);
    }
#pragma unroll
    for (int ni = 0; ni < 4; ni++) {
      u16x8 r = *(const u16x8*)&Bs[(wn * 64 + ni * 16 + lrow) * 40 + lk * 8];
      bfr[ni] = __builtin_bit_cast(bf16x8, r);
    }
#pragma unroll
    for (int mi = 0; mi < 4; mi++)
#pragma unroll
      for (int ni = 0; ni < 4; ni++)
        acc[mi][ni] = __builtin_amdgcn_mfma_f32_16x16x32_bf16(af[mi], bfr[ni], acc[mi][ni], 0, 0, 0);
    __syncthreads();
  }

#pragma unroll
  for (int mi = 0; mi < 4; mi++)
#pragma unroll
    for (int ni = 0; ni < 4; ni++)
#pragma unroll
      for (int reg = 0; reg < 4; reg++) {
        int gr = m0 + wm * 64 + mi * 16 + lk * 4 + reg;
        int gc = n0 + wn * 64 + ni * 16 + lrow;
        if (gc < N) {
          float v = acc[mi][ni][reg] + bias[gc];
          if (mode == 1) {
            if (v < 0.f) v = 0.f;
            Cb[(size_t)gr * ldc + gc] = f2bf(v);
          } else {
            Cf[(size_t)gr * ldc + gc] = v;
          }
        }
      }
}

// ---------------------------------------------------------------------------
// GCN aggregation (deterministic edge order), f32
// ---------------------------------------------------------------------------
__global__ __launch_bounds__(256) void k_agg(
    const float* __restrict__ X, float* __restrict__ Y,
    const float* __restrict__ bias, const int* __restrict__ offs,
    const int* __restrict__ eid, const int* __restrict__ esrc,
    const float* __restrict__ inv, int F, int relu) {
  int n = blockIdx.x;
  int beg = offs[n], end = offs[n + 1];
  float invn = inv[n];
  float inv2 = invn * invn;
  for (int d = threadIdx.x; d < F; d += 256) {
    float acc = 0.f;
    for (int t = beg; t < end; t++) {
      int e = eid[t]; int s = esrc[e];
      float cf = inv[s] * invn;
      acc += X[(size_t)s * F + d] * cf;
    }
    acc += X[(size_t)n * F + d] * inv2;
    acc += bias[d];
    if (relu && acc < 0.f) acc = 0.f;
    Y[(size_t)n * F + d] = acc;
  }
}

// hw2[4096,64] = h[4096,512] @ enc_w2[512,64], all f32 (ranking path)
__global__ __launch_bounds__(256) void k_mmw2(const float* __restrict__ h,
                                              const float* __restrict__ w2,
                                              float* __restrict__ out) {
  __shared__ float hs[4 * 512];
  int tid  = threadIdx.x;
  int brow = blockIdx.x * 4;
  const f32x4* src = (const f32x4*)(h + (size_t)brow * 512);
  f32x4* dst4 = (f32x4*)hs;
  dst4[tid]       = src[tid];
  dst4[tid + 256] = src[tid + 256];
  __syncthreads();
  int r = tid >> 6, c = tid & 63;
  float acc = 0.f;
  const float* hr = hs + r * 512;
#pragma unroll 8
  for (int k = 0; k < 512; k++) acc = fmaf(hr[k], w2[k * 64 + c], acc);
  out[(size_t)(brow + r) * 64 + c] = acc;
}

// local[n] = mean over 32 sub_nodes of spot_emb (+ bf16 copy for decoder)
__global__ void k_pool(const float* __restrict__ spot, const int* __restrict__ sub,
                       float* __restrict__ local, unsigned short* __restrict__ local_bf) {
  int n = blockIdx.x, d = threadIdx.x;  // 64 threads
  float acc = 0.f;
  for (int j = 0; j < 32; j++) {
    int s = sub[n * 32 + j];
    acc += spot[(size_t)s * 64 + d];
  }
  float lv = acc * 0.03125f;
  local[(size_t)n * 64 + d] = lv;
  local_bf[(size_t)n * 64 + d] = f2bf(lv);
}

// Q/K/V packed rows: Qp/Kp/Vp[n][64] = local[n] @ in_w^T + in_b (f32)
__global__ void k_qkv(const float* __restrict__ local, const float* __restrict__ iw,
                      const float* __restrict__ ib,
                      float* __restrict__ Qp, float* __restrict__ Kp, float* __restrict__ Vp) {
  __shared__ float lx[64];
  int n = blockIdx.x, t = threadIdx.x;  // 192 threads
  if (t < 64) lx[t] = local[(size_t)n * 64 + t];
  __syncthreads();
  float acc = 0.f;
#pragma unroll 8
  for (int d = 0; d < 64; d++) acc = fmaf(lx[d], iw[t * 64 + d], acc);
  acc += ib[t];
  if (t < 64)       Qp[(size_t)n * 64 + t] = acc;
  else if (t < 128) Kp[(size_t)n * 64 + (t - 64)] = acc;
  else              Vp[(size_t)n * 64 + (t - 128)] = acc;
}

// ---------------------------------------------------------------------------
// Fused attention v13 (= v11, proven 452us): pass-1 shuffle form (no LDS, no
// barriers), pass-2 staged KtB/Pt with rowavg-in-registers select. v12's
// all-shuffle pass 2 spilled to scratch (WRITE_SIZE 1.1->7.2MB) and regressed;
// this register budget (~96 VGPR) is the measured local optimum.
// Thread roles: scores = (sm 0..63, sq 0..1, shp 0..1); PV = (dq 0..15, me 0..15).
// ---------------------------------------------------------------------------
#define RT 2
__global__ __launch_bounds__(256, 3) void k_attn(
    const float* __restrict__ Qp, const float* __restrict__ Kp, const float* __restrict__ Vp,
    float* __restrict__ ctx, int* __restrict__ sampled) {
  // regA[2][4096] f32 = 32 KB:
  //  after pass1: redM/redZ in regA[0]
  //  pass2: KtB = regA[0]; Pt = regA[1][0..544); rvbuf = regA[1][1024..3072)
  //  epilogue: Osh = regA[0]; select: histT/gaux = (unsigned*)regA[0]
  __shared__ __attribute__((aligned(16))) float regA[2][64 * 64];
  __shared__ float sMZ[2][2][4];   // [M/Z][q][h]
  __shared__ unsigned wtot[4];
  __shared__ unsigned sh_prefix;
  __shared__ int sh_r;

  const int t   = threadIdx.x;
  const int n0  = blockIdx.x * RT;
  const int sm  = t & 63;
  const int sq  = (t >> 6) & 1;
  const int shp = t >> 7;
  const int dq  = t & 15;   // PV: d-quad
  const int me  = t >> 4;   // PV: m-slice
  const int stm = t >> 4;   // staging row within 16-group
  const int stc = t & 15;   // staging col quad
  const int wv  = t >> 6;   // wave id
  const int lane = t & 63;

  // Q fragment for pass 2: wave-uniform address -> broadcast load
  float Qreg[32];
  {
    const float* qp = Qp + (size_t)(n0 + sq) * 64 + shp * 32;
#pragma unroll
    for (int j = 0; j < 8; j++) {
      f32x4 qv = *(const f32x4*)(qp + j * 4);
      Qreg[j * 4 + 0] = qv[0]; Qreg[j * 4 + 1] = qv[1];
      Qreg[j * 4 + 2] = qv[2]; Qreg[j * 4 + 3] = qv[3];
    }
  }

  // ---- pass 1 (shuffle form): online M, Z -- no LDS, no barriers ----
  const int hsel = stc >> 2;   // head handled by this lane
  const int rr   = stc & 3;    // slot within quad; lane's key = stm + 16*rr
  float qsh[2][4];
#pragma unroll
  for (int q = 0; q < 2; q++) {
    f32x4 qv = *(const f32x4*)(Qp + (size_t)(n0 + q) * 64 + stc * 4);
    qsh[q][0] = qv[0]; qsh[q][1] = qv[1]; qsh[q][2] = qv[2]; qsh[q][3] = qv[3];
  }

  float M[2] = {-3.0e38f, -3.0e38f}, Z[2] = {0.f, 0.f};
  {
    f32x4 ka[4], kb[4];
#pragma unroll
    for (int j = 0; j < 4; j++) {
      ka[j] = *(const f32x4*)(Kp + (size_t)(j * 16 + stm) * 64 + stc * 4);
      kb[j] = *(const f32x4*)(Kp + (size_t)(64 + j * 16 + stm) * 64 + stc * 4);
    }
    for (int tp = 0; tp < 64; tp += 2) {
#pragma unroll
      for (int half = 0; half < 2; half++) {
        f32x4 k0 = (half == 0) ? ka[0] : kb[0];
        f32x4 k1 = (half == 0) ? ka[1] : kb[1];
        f32x4 k2 = (half == 0) ? ka[2] : kb[2];
        f32x4 k3 = (half == 0) ? ka[3] : kb[3];
        float s00 = 0.f, s01 = 0.f, s02 = 0.f, s03 = 0.f;
        float s10 = 0.f, s11 = 0.f, s12 = 0.f, s13 = 0.f;
#pragma unroll
        for (int e = 0; e < 4; e++) {
          s00 = fmaf(qsh[0][e], k0[e], s00);
          s01 = fmaf(qsh[0][e], k1[e], s01);
          s02 = fmaf(qsh[0][e], k2[e], s02);
          s03 = fmaf(qsh[0][e], k3[e], s03);
          s10 = fmaf(qsh[1][e], k0[e], s10);
          s11 = fmaf(qsh[1][e], k1[e], s11);
          s12 = fmaf(qsh[1][e], k2[e], s12);
          s13 = fmaf(qsh[1][e], k3[e], s13);
        }
        // prefetch tile tp+2+half (lands in ~1 iteration)
        if (tp + 2 + half < 64) {
#pragma unroll
          for (int j = 0; j < 4; j++) {
            f32x4 v = *(const f32x4*)(Kp + (size_t)((tp + 2 + half) * 64 + j * 16 + stm) * 64 + stc * 4);
            if (half == 0) ka[j] = v; else kb[j] = v;
          }
        }
        // butterfly within quad: sum the 4 dim-partials -> head hsel's score
        s00 += __shfl_xor(s00, 1, 64); s00 += __shfl_xor(s00, 2, 64);
        s01 += __shfl_xor(s01, 1, 64); s01 += __shfl_xor(s01, 2, 64);
        s02 += __shfl_xor(s02, 1, 64); s02 += __shfl_xor(s02, 2, 64);
        s03 += __shfl_xor(s03, 1, 64); s03 += __shfl_xor(s03, 2, 64);
        s10 += __shfl_xor(s10, 1, 64); s10 += __shfl_xor(s10, 2, 64);
        s11 += __shfl_xor(s11, 1, 64); s11 += __shfl_xor(s11, 2, 64);
        s12 += __shfl_xor(s12, 1, 64); s12 += __shfl_xor(s12, 2, 64);
        s13 += __shfl_xor(s13, 1, 64); s13 += __shfl_xor(s13, 2, 64);
        // lane keeps key stm + 16*rr
        float sv0 = (rr == 0) ? s00 : (rr == 1) ? s01 : (rr == 2) ? s02 : s03;
        float sv1 = (rr == 0) ? s10 : (rr == 1) ? s11 : (rr == 2) ? s12 : s13;
        sv0 *= 0.25f; sv1 *= 0.25f;
        if (sv0 > M[0]) { Z[0] = fmaf(Z[0], __expf(M[0] - sv0), 1.0f); M[0] = sv0; }
        else            Z[0] += __expf(sv0 - M[0]);
        if (sv1 > M[1]) { Z[1] = fmaf(Z[1], __expf(M[1] - sv1), 1.0f); M[1] = sv1; }
        else            Z[1] += __expf(sv1 - M[1]);
      }
    }
  }
  // merge M/Z: rows (q*4+h), slot stm+16*rr -- identical partition to v10.
  {
    float* redM = regA[0];
    float* redZ = regA[0] + 512;
    int slot = stm + 16 * rr;
    redM[(0 * 4 + hsel) * 64 + slot] = M[0];
    redM[(1 * 4 + hsel) * 64 + slot] = M[1];
    redZ[(0 * 4 + hsel) * 64 + slot] = Z[0];
    redZ[(1 * 4 + hsel) * 64 + slot] = Z[1];
    __syncthreads();
    if (t < 8) {
      const float* pm = &redM[t * 64];
      const float* pz = &redZ[t * 64];
      float Mv = -3.0e38f, Zv = 0.f;
      for (int i = 0; i < 64; i++) {
        float m_ = pm[i], z_ = pz[i];
        if (m_ > Mv) { Zv = fmaf(Zv, __expf(Mv - m_), z_); Mv = m_; }
        else         Zv = fmaf(z_, __expf(m_ - Mv), Zv);
      }
      sMZ[0][t >> 2][t & 3] = Mv;
      sMZ[1][t >> 2][t & 3] = Zv;
    }
    __syncthreads();
  }
  float Mh[2], iZ[2];
#pragma unroll
  for (int hh = 0; hh < 2; hh++) {
    Mh[hh] = sMZ[0][sq][shp * 2 + hh];
    iZ[hh] = 1.0f / sMZ[1][sq][shp * 2 + hh];
  }
  __syncthreads();   // redM/redZ reads complete before pass-2 overwrites regA

  // ---- pass 2: p -> Pt, rowavg -> rvbuf -> registers, PV accumulate ----
  f32x4 kA[4];
#pragma unroll
  for (int jj = 0; jj < 4; jj++)
    kA[jj] = *(const f32x4*)(Kp + (size_t)(jj * 16 + stm) * 64 + stc * 4);
  float* KtB   = regA[0];
  float* Pt    = regA[1];          // [8][68] floats
  float* rvbuf = regA[1] + 1024;   // [2][16][64] floats (8 KB)
  float o4[2][4];
#pragma unroll
  for (int q = 0; q < 2; q++)
#pragma unroll
    for (int e = 0; e < 4; e++) o4[q][e] = 0.f;
  float rv[2][16];                 // rowavg for keys (wv*16+g)*64+lane

  for (int sb = 0; sb < 4; sb++) {
    for (int ti = 0; ti < 16; ti++) {
      const int tile = sb * 16 + ti;
#pragma unroll
      for (int jj = 0; jj < 4; jj++) {
        int m = jj * 16 + stm;
        int sc = (stc + (m & 15) + 4 * (m >> 4)) & 15;
        *(f32x4*)&KtB[(m * 16 + sc) * 4] = kA[jj];
      }
      __syncthreads();                                   // B1: KtB ready, Pt free
      if (tile + 1 < 64) {
#pragma unroll
        for (int jj = 0; jj < 4; jj++)
          kA[jj] = *(const f32x4*)(Kp + (size_t)((tile + 1) * 64 + jj * 16 + stm) * 64 + stc * 4);
      }
      {
        float s[2] = {0.f, 0.f};
#pragma unroll
        for (int ci = 0; ci < 8; ci++) {
          int c = shp * 8 + ci;
          int sc = (c + (sm & 15) + 4 * (sm >> 4)) & 15;
          f32x4 k4 = *(const f32x4*)&KtB[(sm * 16 + sc) * 4];
          int hh = ci >> 2;
#pragma unroll
          for (int e = 0; e < 4; e++)
            s[hh] = fmaf(Qreg[ci * 4 + e], k4[e], s[hh]);
        }
#pragma unroll
        for (int hh = 0; hh < 2; hh++) {
          float p = __expf(s[hh] * 0.25f - Mh[hh]) * iZ[hh];
          Pt[(sq * 4 + shp * 2 + hh) * 68 + sm] = p;
        }
      }
      // V straight from global/L2 (independent of Pt; hides under the barrier)
      f32x4 vt[4];
#pragma unroll
      for (int i = 0; i < 4; i++)
        vt[i] = *(const f32x4*)(Vp + (size_t)(tile * 64 + me * 4 + i) * 64 + dq * 4);
      __syncthreads();                                   // B2: Pt ready
      // rowavg capture: owning wave (wv == sb) computes both q values for
      // (tile, sm=lane) -- bit-identical arithmetic to the old rowbuf write.
      if (wv == sb) {
        rvbuf[(0 * 16 + ti) * 64 + lane] =
            0.25f * (Pt[0 * 68 + lane] + Pt[1 * 68 + lane] +
                     Pt[2 * 68 + lane] + Pt[3 * 68 + lane]);
        rvbuf[(1 * 16 + ti) * 64 + lane] =
            0.25f * (Pt[4 * 68 + lane] + Pt[5 * 68 + lane] +
                     Pt[6 * 68 + lane] + Pt[7 * 68 + lane]);
      }
      {
        int h = dq >> 2;
        f32x4 p4[2];
#pragma unroll
        for (int q = 0; q < 2; q++)
          p4[q] = *(const f32x4*)&Pt[(q * 4 + h) * 68 + me * 4];
#pragma unroll
        for (int i = 0; i < 4; i++) {
#pragma unroll
          for (int q = 0; q < 2; q++)
#pragma unroll
            for (int e = 0; e < 4; e++)
              o4[q][e] = fmaf(p4[q][i], vt[i][e], o4[q][e]);
        }
      }
      // no 3rd barrier: next B1 protects Pt; KtB staging races nothing live
    }
    // copy this super-block's rowavg into registers (own-wave data; static g)
    if (wv == sb) {
#pragma unroll
      for (int g = 0; g < 16; g++) {
        rv[0][g] = rvbuf[(0 * 16 + g) * 64 + lane];
        rv[1][g] = rvbuf[(1 * 16 + g) * 64 + lane];
      }
    }
  }

  // ---- PV cross-slice reduction (deterministic) ----
  {
    float* Osh = regA[0];   // KtB dead after last tile's score reads
#pragma unroll
    for (int q = 0; q < 2; q++)
#pragma unroll
      for (int e = 0; e < 4; e++)
        Osh[((me * 2 + q) * 16 + dq) * 4 + e] = o4[q][e];
    __syncthreads();
    if (t < 128) {
      int q2 = t >> 6, d = t & 63;
      float acc = 0.f;
      for (int i = 0; i < 16; i++)
        acc += Osh[((i * 2 + q2) * 16 + (d >> 2)) * 4 + (d & 3)];
      ctx[(size_t)(n0 + q2) * 64 + d] = acc;
    }
    __syncthreads();
  }

  // ---- per-row radix select from REGISTERS (Threefry rank; ties -> lowest) ----
  unsigned* histT = (unsigned*)regA[0];        // [4][256]
  unsigned* gaux  = ((unsigned*)regA[0]) + 1024; // gcnts[64] @0, gpref[64] @64
#pragma unroll
  for (int q = 0; q < RT; q++) {
    int n = n0 + q;
    if (t == 0) {
      unsigned a0, a1, b0, b1;
      tf2x32(0u, 42u, 0u, 2u, a0, a1);
      tf2x32(0u, 42u, 1u, 3u, b0, b1);
      unsigned o0, o1, bits;
      if (n < 2048) { tf2x32(a1, b1, (unsigned)n, (unsigned)(n + 2048), o0, o1); bits = o0; }
      else          { tf2x32(a1, b1, (unsigned)(n - 2048), (unsigned)n, o0, o1); bits = o1; }
      sh_r = (int)(bits & 1023u);
      sh_prefix = 0u;
    }
    __syncthreads();
    int r = sh_r;
    unsigned prefix = 0u;
    for (int level = 0; level < 4; level++) {
      int shift = 24 - 8 * level;
      unsigned c0 = 0, c1 = 0, c2 = 0, c3 = 0;
#pragma unroll
      for (int g = 0; g < 16; g++) {
        unsigned u = __float_as_uint(rv[q][g]);
        bool ok = (level == 0) || ((u >> (shift + 8)) == (prefix >> (shift + 8)));
        unsigned bin = (u >> shift) & 255u;
        unsigned long long mok = __ballot(ok);
        unsigned long long b0 = __ballot(bin & 1u);
        unsigned long long b1 = __ballot(bin & 2u);
        unsigned long long b2 = __ballot(bin & 4u);
        unsigned long long b3 = __ballot(bin & 8u);
        unsigned long long b4 = __ballot(bin & 16u);
        unsigned long long b5 = __ballot(bin & 32u);
        unsigned long long b6 = __ballot(bin & 64u);
        unsigned long long b7 = __ballot(bin & 128u);
        unsigned long long m = mok;
        m &= (lane & 1)  ? b0 : ~b0;
        m &= (lane & 2)  ? b1 : ~b1;
        m &= (lane & 4)  ? b2 : ~b2;
        m &= (lane & 8)  ? b3 : ~b3;
        m &= (lane & 16) ? b4 : ~b4;
        m &= (lane & 32) ? b5 : ~b5;
        c0 += (unsigned)__builtin_popcountll(m & ~b6 & ~b7);
        c1 += (unsigned)__builtin_popcountll(m &  b6 & ~b7);
        c2 += (unsigned)__builtin_popcountll(m & ~b6 &  b7);
        c3 += (unsigned)__builtin_popcountll(m &  b6 &  b7);
      }
      histT[wv * 256 + lane]       = c0;
      histT[wv * 256 + 64 + lane]  = c1;
      histT[wv * 256 + 128 + lane] = c2;
      histT[wv * 256 + 192 + lane] = c3;
      __syncthreads();
      unsigned own = histT[t] + histT[256 + t] + histT[512 + t] + histT[768 + t];
      unsigned v = own;
      for (int off = 1; off < 64; off <<= 1) {
        unsigned u2 = __shfl_up(v, off, 64);
        if ((t & 63) >= off) v += u2;
      }
      if ((t & 63) == 63) wtot[t >> 6] = v;
      __syncthreads();
      unsigned basev = 0;
#pragma unroll
      for (int w = 0; w < 4; w++) if (w < (t >> 6)) basev += wtot[w];
      v += basev;
      unsigned cb = v - own;
      if ((unsigned)r >= cb && (unsigned)r < v) {
        sh_prefix = prefix | ((unsigned)t << shift);
        sh_r = r - (int)cb;
      }
      __syncthreads();
      prefix = sh_prefix; r = sh_r;
    }
    // extraction: rank-r among {idx : bits(idx)==prefix}, ascending idx
    {
      unsigned long long msk[16];
#pragma unroll
      for (int g = 0; g < 16; g++)
        msk[g] = __ballot(__float_as_uint(rv[q][g]) == prefix);
      if (lane == 0) {
#pragma unroll
        for (int g = 0; g < 16; g++)
          gaux[wv * 16 + g] = (unsigned)__builtin_popcountll(msk[g]);
      }
      __syncthreads();
      if (t < 64) {
        unsigned acc = 0;
        for (int i = 0; i < t; i++) acc += gaux[i];
        gaux[64 + t] = acc;
      }
      __syncthreads();
#pragma unroll
      for (int g = 0; g < 16; g++) {
        if (__float_as_uint(rv[q][g]) == prefix) {
          unsigned before = (unsigned)__builtin_popcountll(msk[g] & ((1ull << lane) - 1ull));
          if ((int)(gaux[64 + wv * 16 + g] + before) == r)
            sampled[n] = (wv * 16 + g) * 64 + lane;
        }
      }
      __syncthreads();
    }
  }
}

// global_niches = ctx @ out_w^T + out_b  (f32)
__global__ void k_outproj(const float* __restrict__ ctx, const float* __restrict__ ow,
                          const float* __restrict__ ob, float* __restrict__ gni) {
  __shared__ float cx[64];
  int n = blockIdx.x, t = threadIdx.x;  // 64 threads
  cx[t] = ctx[(size_t)n * 64 + t];
  __syncthreads();
  float acc = 0.f;
#pragma unroll 8
  for (int j = 0; j < 64; j++) acc = fmaf(cx[j], ow[t * 64 + j], acc);
  gni[(size_t)n * 64 + t] = acc + ob[t];
}

// bilinear discriminator logits (pos & neg), f32 outputs
__global__ void k_logits(const float* __restrict__ local, const float* __restrict__ gni,
                         const int* __restrict__ sampled,
                         const float* __restrict__ bw, const float* __restrict__ bb,
                         float* __restrict__ outp, float* __restrict__ outn) {
  __shared__ float lv[64], gp[64], gn[64];
  int n = blockIdx.x, t = threadIdx.x;  // 64 threads
  int sm = sampled[n];
  lv[t] = local[(size_t)n * 64 + t];
  gp[t] = gni[(size_t)n * 64 + t];
  gn[t] = gni[(size_t)sm * 64 + t];
  __syncthreads();
  float tp = 0.f, tn = 0.f;
#pragma unroll 8
  for (int e = 0; e < 64; e++) {
    float w = bw[t * 64 + e];
    tp = fmaf(w, gp[e], tp);
    tn = fmaf(w, gn[e], tn);
  }
  float vp = lv[t] * tp, vn = lv[t] * tn;
  for (int off = 32; off; off >>= 1) {
    vp += __shfl_down(vp, off, 64);
    vn += __shfl_down(vn, off, 64);
  }
  if (t == 0) {
    outp[n] = vp + bb[0];
    outn[n] = vn + bb[0];
  }
}

// ---------------------------------------------------------------------------
extern "C" void kernel_launch(void* const* d_in, const int* in_sizes, int n_in,
                              void* d_out, int out_size, void* d_ws, size_t ws_size,
                              hipStream_t stream) {
  const float* x      = (const float*)d_in[0];
  const int*   edge   = (const int*)d_in[1];
  const int*   sub    = (const int*)d_in[2];
  const float* enc_w1 = (const float*)d_in[3];
  const float* enc_b1 = (const float*)d_in[4];
  const float* enc_w2 = (const float*)d_in[5];
  const float* enc_b2 = (const float*)d_in[6];
  const float* dec_w1 = (const float*)d_in[7];
  const float* dec_b1 = (const float*)d_in[8];
  const float* dec_w2 = (const float*)d_in[9];
  const float* dec_b2 = (const float*)d_in[10];
  const float* ain_w  = (const float*)d_in[11];
  const float* ain_b  = (const float*)d_in[12];
  const float* aout_w = (const float*)d_in[13];
  const float* aout_b = (const float*)d_in[14];
  const float* bil_w  = (const float*)d_in[15];
  const float* bil_b  = (const float*)d_in[16];
  float* out = (float*)d_out;

  const int E = in_sizes[1] / 2;  // 49152
  const int* esrc = edge;
  const int* edst = edge + E;

  // ---- time-overlapped workspace (~19.8 MB) ----
  char* base = (char*)d_ws;
  const size_t MB = (size_t)1 << 20;
  float*          cpart    = (float*)(base + 0);             // [conv1..combine] 16MB (2 x 8MB)
  float*          h_pre    = (float*)(base + 0);             // = cpart slice 0, [combine..agg1]
  unsigned short* dech_bf  = (unsigned short*)(base + 0);    // [dec1..dec2] 4MB
  float*          h        = (float*)(base + 8*MB);          // [agg1..mmw2] 8MB
  float*          Qp       = (float*)(base + 8*MB);          // [qkv..attn] 1MB
  float*          Kp       = (float*)(base + 9*MB);          // [qkv..attn] 1MB
  float*          Vp       = (float*)(base + 10*MB);         // [qkv..attn] 1MB
  float*          ctx      = (float*)(base + 11*MB);         // [attn..outproj] 1MB
  float*          gni      = (float*)(base + 12*MB);         // [outproj..logits] 1MB
  float*          hw2      = (float*)(base + 16*MB);         // [mmw2..agg2] 1MB
  float*          spot     = (float*)(base + 17*MB);         // [agg2..pool] 1MB
  float*          localf   = (float*)(base + 18*MB);         // [pool..logits] 1MB
  unsigned short* local_bf = (unsigned short*)(base + 19*MB);// [pool..dec1] 0.5MB
  char* ip = base + 19*MB + 512*1024;
  float* inv    = (float*)ip;  ip += 16384;
  int*   degcnt = (int*)ip;    ip += 16384;  // zeroed
  int*   cursor = (int*)ip;    ip += 16384;  // zeroed
  int*   offs   = (int*)ip;    ip += 16640;
  int*   sampled= (int*)ip;    ip += 16384;
  int*   eid    = (int*)ip;    ip += (size_t)E * 4;

  hipMemsetAsync(degcnt, 0, (size_t)NN * 4, stream);
  hipMemsetAsync(cursor, 0, (size_t)NN * 4, stream);

  int egrid = (E + 255) / 256;
  k_deg<<<egrid, 256, 0, stream>>>(edst, degcnt, E);
  k_inv<<<(NN + 255) / 256, 256, 0, stream>>>(degcnt, inv);
  k_scan<<<1, 1024, 0, stream>>>(degcnt, offs);
  k_scatter<<<egrid, 256, 0, stream>>>(edst, offs, cursor, eid, E);
  k_sort<<<(NN + 255) / 256, 256, 0, stream>>>(offs, eid);

  // encoder conv1: f32, split-K=2 + deterministic combine
  {
    dim3 g(4, 32, 2);
    k_gemm_f32<<<g, 256, 0, stream>>>(x, enc_w1, cpart);
  }
  k_combine<<<(NN * 512 / 4) / 256, 256, 0, stream>>>(h_pre, cpart + (size_t)NN * 512);
  k_agg<<<NN, 256, 0, stream>>>(h_pre, h, enc_b1, offs, eid, esrc, inv, 512, 1);
  k_mmw2<<<NN / 4, 256, 0, stream>>>(h, enc_w2, hw2);
  k_agg<<<NN, 256, 0, stream>>>(hw2, spot, enc_b2, offs, eid, esrc, inv, 64, 0);
  k_pool<<<NN, 64, 0, stream>>>(spot, sub, localf, local_bf);

  // decoder (bf16 MFMA, f32 weights converted on the fly)
  {
    dim3 g(4, 32);
    k_gemm_bf<<<g, 256, 0, stream>>>(local_bf, dec_w1, nullptr, dech_bf, dec_b1,
                                     NN, 512, 64, 512, 1);
  }
  {
    dim3 g(24, 32);
    k_gemm_bf<<<g, 256, 0, stream>>>(dech_bf, dec_w2, out, nullptr, dec_b2,
                                     NN, INDIM, 512, INDIM, 2);
  }

  // attention (f32 ranking path, fused stats+avg+ctx+select)
  k_qkv<<<NN, 192, 0, stream>>>(localf, ain_w, ain_b, Qp, Kp, Vp);
  k_attn<<<NN / RT, 256, 0, stream>>>(Qp, Kp, Vp, ctx, sampled);
  k_outproj<<<NN, 64, 0, stream>>>(ctx, aout_w, aout_b, gni);
  k_logits<<<NN, 64, 0, stream>>>(localf, gni, sampled, bil_w, bil_b,
                                  out + RECON_ELEMS, out + RECON_ELEMS + NN);
}